// Round 6
// baseline (1688.462 us; speedup 1.0000x reference)
//
#include <hip/hip_runtime.h>
#include <hip/hip_bf16.h>

#define N_ROWS 32768
#define K_CODES 4096
#define D_DIM 256
#define CAP 64
#define MARGIN_T 2e-3f

// ---- d_ws layout (bytes) -- total 4,882,432 (< R1-proven ~5 MB) ----
#define WS_COUNTS    0          // float[4096]
#define WS_LOSSP     16384      // float[32768]
#define WS_IDX       147456     // int[32768]
#define WS_Z2        278528     // float[32768]
#define WS_E2        409600     // float[4096]
#define WS_RMAX      425984     // uint[32768]
#define WS_CNT       557056     // int[32768]
#define WS_DW        688128     // float[1048576] -> ends 4882432

// ---- d_out scratch (inside out_zq's 33.5 MB span; dead until k3 rewrites) ----
#define DO_ZB        0          // ushort[32768*256] = 16 MB
#define DO_WB        16777216   // ushort[4096*256]  =  2 MB
#define DO_CAND      18874368   // int[32768*64]     =  8 MB -> ends 27262976

typedef __attribute__((ext_vector_type(8)))  short bf16x8;
typedef __attribute__((ext_vector_type(16))) float f32x16;
typedef __attribute__((ext_vector_type(8)))  unsigned short us8;

// ---------------------------------------------------------------------------
// K1: z2/e2 with numpy's exact pairwise structure (proven in R1)
// ---------------------------------------------------------------------------
__global__ void k1_norms(const float* __restrict__ z, const float* __restrict__ w,
                         float* __restrict__ z2, float* __restrict__ e2)
{
#pragma clang fp contract(off)
    int gid = blockIdx.x * blockDim.x + threadIdx.x;
    const float* row;
    float* outp;
    if (gid < N_ROWS) { row = z + (size_t)gid * D_DIM; outp = z2 + gid; }
    else if (gid < N_ROWS + K_CODES) { row = w + (size_t)(gid - N_ROWS) * D_DIM; outp = e2 + (gid - N_ROWS); }
    else return;

    float total = 0.0f;
    for (int half = 0; half < 2; half++) {
        const float* x = row + half * 128;
        float r[8];
#pragma unroll
        for (int j = 0; j < 8; j++) { float v = x[j]; r[j] = v * v; }
        for (int i = 8; i < 128; i += 8) {
#pragma unroll
            for (int j = 0; j < 8; j++) { float v = x[i + j]; r[j] += v * v; }
        }
        float s = ((r[0] + r[1]) + (r[2] + r[3])) + ((r[4] + r[5]) + (r[6] + r[7]));
        if (half == 0) total = s; else total = total + s;
    }
    *outp = total;
}

// ---------------------------------------------------------------------------
// KCONV: fp32 -> bf16 (RNE), 8 elems/thread. z then w.
// ---------------------------------------------------------------------------
__device__ inline unsigned short f2b(float f) {
    __hip_bfloat16 h = __float2bfloat16(f);
    return *(unsigned short*)&h;
}

__global__ void kconv(const float* __restrict__ z, const float* __restrict__ w,
                      unsigned short* __restrict__ zb, unsigned short* __restrict__ wb)
{
    size_t i = (size_t)(blockIdx.x * 256 + threadIdx.x) * 8;
    const float* src; unsigned short* dst;
    const size_t NZ = (size_t)N_ROWS * D_DIM;
    if (i < NZ) { src = z + i; dst = zb + i; }
    else        { size_t j = i - NZ; src = w + j; dst = wb + j; }
    float4 a = *(const float4*)src;
    float4 b = *(const float4*)(src + 4);
    us8 o;
    o[0] = f2b(a.x); o[1] = f2b(a.y); o[2] = f2b(a.z); o[3] = f2b(a.w);
    o[4] = f2b(b.x); o[5] = f2b(b.y); o[6] = f2b(b.z); o[7] = f2b(b.w);
    *(us8*)dst = o;
}

// ---------------------------------------------------------------------------
// K2 (two phases): bf16 MFMA GEMM t = W @ Z^T, 128-code x 128-row tiles.
// 256 thr = 4 waves (2x2), wave tile 64x64, 32x32x16 MFMA.
// Staging: R1-proven pattern — us8 global loads -> registers -> LDS stores,
// double-buffered 64 KiB, ONE barrier per chunk (no global_load_lds).
// PHASE 0: per-row max t~ -> atomicMax (ordered-uint key).
// PHASE 1: bit-identical recompute; append codes with t~ >= rowmax - margin.
// ---------------------------------------------------------------------------
template<int PHASE>
__global__ __launch_bounds__(256, 2) void k2_pass(
    const unsigned short* __restrict__ zb, const unsigned short* __restrict__ wb,
    unsigned int* __restrict__ rowmaxkey, int* __restrict__ cnt,
    int* __restrict__ cand)
{
    __shared__ char smem[65536];
    const int tid  = threadIdx.x;
    const int lane = tid & 63;
    const int wid  = tid >> 6;
    const int wr   = wid >> 1;
    const int wc   = wid & 1;
    const int rowBase  = blockIdx.x * 128;
    const int codeBase = blockIdx.y * 2048;
    const int m = lane & 31;

    int rown[2];
#pragma unroll
    for (int ns = 0; ns < 2; ns++) rown[ns] = rowBase + wc * 64 + ns * 32 + m;

    float thr[2];
    if (PHASE == 1) {
#pragma unroll
        for (int ns = 0; ns < 2; ns++) {
            unsigned u = rowmaxkey[rown[ns]];
            int b = (u & 0x80000000u) ? (int)(u ^ 0x80000000u) : (int)~u;
            thr[ns] = __int_as_float(b) - MARGIN_T;
        }
    }

    us8 va[4], vb[4];
    auto load_regs = [&](int c) {
        int ct = c >> 2, ch = c & 3;
        int col8 = ch * 64 + wid * 16 + (lane >> 5) * 8;
#pragma unroll
        for (int g = 0; g < 4; g++) {
            int arow = codeBase + ct * 128 + g * 32 + m;
            int brow = rowBase + g * 32 + m;
            va[g] = *(const us8*)(wb + (size_t)arow * D_DIM + col8);
            vb[g] = *(const us8*)(zb + (size_t)brow * D_DIM + col8);
        }
    };
    auto write_lds = [&](int buf) {
        char* Ab = smem + buf * 32768;
        char* Bb = Ab + 16384;
#pragma unroll
        for (int g = 0; g < 4; g++) {
            *(us8*)(Ab + (size_t)((wid * 4 + g) * 64 + lane) * 16) = va[g];
            *(us8*)(Bb + (size_t)((wid * 4 + g) * 64 + lane) * 16) = vb[g];
        }
    };

    f32x16 acc[2][2];
    float tmax[2] = {-1e30f, -1e30f};

    load_regs(0);
    write_lds(0);

    const int NCH = 64;                  // 16 code-tiles * 4 d-chunks
    for (int c = 0; c < NCH; c++) {
        const int buf = c & 1;
        __syncthreads();
        if (c + 1 < NCH) {
            load_regs(c + 1);
            write_lds(buf ^ 1);
        }
        const char* Ab = smem + buf * 32768;
        const char* Bb = Ab + 16384;
        if ((c & 3) == 0) {
            f32x16 zz = {};
#pragma unroll
            for (int ms = 0; ms < 2; ms++)
#pragma unroll
                for (int ns = 0; ns < 2; ns++) acc[ms][ns] = zz;
        }
#pragma unroll
        for (int s = 0; s < 4; s++) {
            bf16x8 af[2], bfr[2];
#pragma unroll
            for (int ms = 0; ms < 2; ms++)
                af[ms] = *(const bf16x8*)(Ab + (size_t)(s * 256 + (wr * 2 + ms) * 64 + lane) * 16);
#pragma unroll
            for (int ns = 0; ns < 2; ns++)
                bfr[ns] = *(const bf16x8*)(Bb + (size_t)(s * 256 + (wc * 2 + ns) * 64 + lane) * 16);
#pragma unroll
            for (int ms = 0; ms < 2; ms++)
#pragma unroll
                for (int ns = 0; ns < 2; ns++)
                    acc[ms][ns] = __builtin_amdgcn_mfma_f32_32x32x16_bf16(
                        af[ms], bfr[ns], acc[ms][ns], 0, 0, 0);
        }
        if ((c & 3) == 3) {
            const int ct = c >> 2;
            if (PHASE == 0) {
#pragma unroll
                for (int ms = 0; ms < 2; ms++)
#pragma unroll
                    for (int ns = 0; ns < 2; ns++)
#pragma unroll
                        for (int r = 0; r < 16; r++)
                            tmax[ns] = fmaxf(tmax[ns], acc[ms][ns][r]);
            } else {
#pragma unroll
                for (int ms = 0; ms < 2; ms++)
#pragma unroll
                    for (int ns = 0; ns < 2; ns++)
#pragma unroll
                        for (int r = 0; r < 16; r++) {
                            float v = acc[ms][ns][r];
                            if (v >= thr[ns]) {
                                int code = codeBase + ct * 128 + wr * 64 + ms * 32
                                         + ((r & 3) + 8 * (r >> 2) + 4 * (lane >> 5));
                                int n = rown[ns];
                                int slot = atomicAdd(&cnt[n], 1);
                                if (slot < CAP) cand[(size_t)n * CAP + slot] = code;
                            }
                        }
            }
        }
    }

    if (PHASE == 0) {
#pragma unroll
        for (int ns = 0; ns < 2; ns++) {
            float o = __shfl_xor(tmax[ns], 32);
            float mx = fmaxf(tmax[ns], o);
            if (lane < 32) {
                int b = __float_as_int(mx);
                unsigned key = (unsigned)b ^ ((unsigned)(b >> 31) | 0x80000000u);
                atomicMax(&rowmaxkey[rown[ns]], key);
            }
        }
    }
}

// ---------------------------------------------------------------------------
// K_RESCORE v3: one WAVE (64 thr) per row. Candidates processed in batches
// of 32: staging iteration j loads candidate j's ENTIRE 1KB row with one
// coalesced float4 instruction (lane = d4) into LDS (stride 65 granules,
// bank-spread); then lane i runs candidate i's serial 256-FMA chain from
// LDS (ascending d, single accumulator = bit-identical to BLAS sgemm).
// Wave-wide lexicographic (d,k) butterfly -> first-index tie-break.
// Fallback full 4096 scan if cnt==0 or cnt>CAP.
// ---------------------------------------------------------------------------
__global__ __launch_bounds__(64) void k_rescore(
    const float* __restrict__ z, const float* __restrict__ w,
    const float* __restrict__ z2, const float* __restrict__ e2,
    const int* __restrict__ cnt, const int* __restrict__ cand,
    int* __restrict__ idx_out)
{
#pragma clang fp contract(off)
    const int lane = threadIdx.x;
    const int n    = blockIdx.x;

    __shared__ float4 wst[32 * 65];   // 33280 B, slot i at wst[i*65 + d4]
    __shared__ float4 zst[64];        // z row, 1 KB

    zst[lane] = ((const float4*)(z + (size_t)n * D_DIM))[lane];

    int c = cnt[n];
    const bool fallback = (c <= 0) || (c > CAP);
    const int total = fallback ? K_CODES : c;

    float bd = __builtin_inff(); int bk = K_CODES;
    const float z2v = z2[n];

    for (int base = 0; base < total; base += 32) {
        int nb = total - base; if (nb > 32) nb = 32;
        // ---- stage nb candidate rows, one coalesced 1KB load per row ----
        for (int j = 0; j < nb; j++) {
            int k = fallback ? (base + j) : cand[(size_t)n * CAP + base + j];
            if ((unsigned)k >= (unsigned)K_CODES) k = 0;   // defensive
            wst[j * 65 + lane] = ((const float4*)(w + (size_t)k * D_DIM))[lane];
        }
        __syncthreads();
        // ---- serial exact chain, one candidate per lane ----
        if (lane < nb) {
            int k = fallback ? (base + lane) : cand[(size_t)n * CAP + base + lane];
            if ((unsigned)k >= (unsigned)K_CODES) k = 0;   // defensive
            const float4* wp = &wst[lane * 65];
            float tacc = 0.0f;
#pragma unroll
            for (int d4 = 0; d4 < 64; d4++) {
                float4 wv = wp[d4];
                float4 zv = zst[d4];
                tacc = __builtin_fmaf(zv.x, wv.x, tacc);
                tacc = __builtin_fmaf(zv.y, wv.y, tacc);
                tacc = __builtin_fmaf(zv.z, wv.z, tacc);
                tacc = __builtin_fmaf(zv.w, wv.w, tacc);
            }
            float u  = z2v - 2.0f * tacc;   // 2*tacc exact -> single rounding
            float dv = u + e2[k];
            if (dv < bd || (dv == bd && k < bk)) { bd = dv; bk = k; }
        }
        __syncthreads();
    }

#pragma unroll
    for (int off = 1; off < 64; off <<= 1) {
        float od = __shfl_xor(bd, off);
        int   ok = __shfl_xor(bk, off);
        if (od < bd || (od == bd && ok < bk)) { bd = od; bk = ok; }
    }
    if (lane == 0) idx_out[n] = bk;
}

// ---------------------------------------------------------------------------
// K3: gather z_q, STE output, loss partials, counts + dw atomics.
// ---------------------------------------------------------------------------
__global__ void k3_scatter(const float* __restrict__ z, const float* __restrict__ w,
                           const int* __restrict__ idx_in,
                           float* __restrict__ counts, float* __restrict__ lossp,
                           float* __restrict__ dw, float* __restrict__ out_zq,
                           float* __restrict__ out_idx)
{
#pragma clang fp contract(off)
    const int n = blockIdx.x;
    const int t = threadIdx.x;
    int idx = idx_in[n];
    if (idx < 0) idx = 0;
    if (idx >= K_CODES) idx = K_CODES - 1;     // defensive clamp (no fault)
    if (t == 0) {
        out_idx[n] = (float)idx;
        atomicAdd(&counts[idx], 1.0f);
    }
    float zv = z[(size_t)n * D_DIM + t];
    float wq = w[(size_t)idx * D_DIM + t];
    out_zq[(size_t)n * D_DIM + t] = zv + (wq - zv);
    float df = zv - wq;
    float sq = df * df;
    atomicAdd(&dw[(size_t)idx * D_DIM + t], zv);

    __shared__ float red[256];
    red[t] = sq; __syncthreads();
    for (int s = 128; s > 0; s >>= 1) {
        if (t < s) red[t] += red[t + s];
        __syncthreads();
    }
    if (t == 0) lossp[n] = red[0];
}

// ---------------------------------------------------------------------------
// K4: vq_loss finalize + new_cs (Laplace smoothing). Single block, 1024 thr.
// ---------------------------------------------------------------------------
__global__ void k4_cs(const float* __restrict__ lossp, const float* __restrict__ counts,
                      const float* __restrict__ cs_in, float* __restrict__ out_loss,
                      float* __restrict__ out_cs)
{
#pragma clang fp contract(off)
    const int t = threadIdx.x;
    __shared__ float red[1024];
    __shared__ float pre[K_CODES];

    float s = 0.0f;
    for (int i = t; i < N_ROWS; i += 1024) s += lossp[i];
    red[t] = s; __syncthreads();
    for (int st = 512; st > 0; st >>= 1) {
        if (t < st) red[t] += red[t + st];
        __syncthreads();
    }
    if (t == 0) out_loss[0] = 0.25f * (red[0] / 8388608.0f);
    __syncthreads();

    const float DEC = 0.99f;
    const float OMD = (float)(1.0 - 0.99);
    float mine[4];
#pragma unroll
    for (int q = 0; q < 4; q++) {
        int k = t + q * 1024;
        float t1 = DEC * cs_in[k];
        float t2 = OMD * counts[k];
        float p = t1 + t2;
        pre[k] = p; mine[q] = p;
    }
    float psum = (mine[0] + mine[1]) + (mine[2] + mine[3]);
    red[t] = psum; __syncthreads();
    for (int st = 512; st > 0; st >>= 1) {
        if (t < st) red[t] += red[t + st];
        __syncthreads();
    }
    float nsum = red[0];
    const float KEPS = (float)(4096.0 * 1e-5);
    float denom = nsum + KEPS;
#pragma unroll
    for (int q = 0; q < 4; q++) {
        int k = t + q * 1024;
        float v = ((pre[k] + 1e-5f) / denom) * nsum;
        out_cs[k] = v;
    }
}

// ---------------------------------------------------------------------------
// K5: new_ema_w = 0.99*ema_w + 0.01*dw ; new_weight = new_ema_w / new_cs[k]
// ---------------------------------------------------------------------------
__global__ void k5_emaw(const float* __restrict__ ema_w, const float* __restrict__ dw,
                        const float* __restrict__ newcs, float* __restrict__ out_w,
                        float* __restrict__ out_emaw)
{
#pragma clang fp contract(off)
    const int i = blockIdx.x * 256 + threadIdx.x;
    const int k = i >> 8;
    const float OMD = (float)(1.0 - 0.99);
    float t1 = 0.99f * ema_w[i];
    float t2 = OMD * dw[i];
    float ne = t1 + t2;
    out_emaw[i] = ne;
    out_w[i] = ne / newcs[k];
}

extern "C" void kernel_launch(void* const* d_in, const int* in_sizes, int n_in,
                              void* d_out, int out_size, void* d_ws, size_t ws_size,
                              hipStream_t stream)
{
    const float* z    = (const float*)d_in[0];
    const float* w    = (const float*)d_in[1];
    const float* cs   = (const float*)d_in[2];
    const float* emaw = (const float*)d_in[3];

    float* out      = (float*)d_out;
    float* out_zq   = out;                    // 8388608
    float* out_idx  = out + 8388608;          // 32768
    float* out_loss = out + 8421376;          // 1
    float* out_w    = out + 8421377;          // 1048576
    float* out_cs   = out + 9469953;          // 4096
    float* out_emaw = out + 9474049;          // 1048576

    char* ws = (char*)d_ws;
    float*          counts  = (float*)(ws + WS_COUNTS);
    float*          lossp   = (float*)(ws + WS_LOSSP);
    int*            idx_int = (int*)  (ws + WS_IDX);
    float*          z2      = (float*)(ws + WS_Z2);
    float*          e2      = (float*)(ws + WS_E2);
    unsigned int*   rmax    = (unsigned int*)(ws + WS_RMAX);
    int*            cnt     = (int*)  (ws + WS_CNT);
    float*          dw      = (float*)(ws + WS_DW);

    // big scratch lives in d_out's out_zq span (dead until k3 rewrites it)
    char* ob = (char*)d_out;
    unsigned short* zb   = (unsigned short*)(ob + DO_ZB);
    unsigned short* wb   = (unsigned short*)(ob + DO_WB);
    int*            cand = (int*)           (ob + DO_CAND);

    hipMemsetAsync(counts, 0, K_CODES * sizeof(float), stream);
    hipMemsetAsync(dw, 0, (size_t)K_CODES * D_DIM * sizeof(float), stream);
    hipMemsetAsync(rmax, 0, N_ROWS * sizeof(unsigned int), stream);
    hipMemsetAsync(cnt, 0, N_ROWS * sizeof(int), stream);

    k1_norms<<<(N_ROWS + K_CODES) / 256, 256, 0, stream>>>(z, w, z2, e2);
    kconv<<<(N_ROWS + K_CODES) * D_DIM / (256 * 8), 256, 0, stream>>>(z, w, zb, wb);

    dim3 g2(N_ROWS / 128, 2);
    k2_pass<0><<<g2, 256, 0, stream>>>(zb, wb, rmax, cnt, cand);
    k2_pass<1><<<g2, 256, 0, stream>>>(zb, wb, rmax, cnt, cand);

    k_rescore<<<N_ROWS, 64, 0, stream>>>(z, w, z2, e2, cnt, cand, idx_int);

    k3_scatter<<<N_ROWS, 256, 0, stream>>>(z, w, idx_int, counts, lossp,
                                           dw, out_zq, out_idx);

    k4_cs<<<1, 1024, 0, stream>>>(lossp, counts, cs, out_loss, out_cs);

    k5_emaw<<<K_CODES, 256, 0, stream>>>(emaw, dw, out_cs, out_w, out_emaw);
}

// Round 7
// 605.167 us; speedup vs baseline: 2.7901x; 2.7901x over previous
//
#include <hip/hip_runtime.h>
#include <hip/hip_bf16.h>

#define N_ROWS 32768
#define K_CODES 4096
#define D_DIM 256
#define CAP 128
#define MARGIN_T 1e-3f
#define RB 8

// ---- d_ws layout (bytes) -- total 4,882,432 (< R1-proven ~5 MB) ----
#define WS_COUNTS    0          // float[4096]
#define WS_LOSSP     16384      // float[32768]
#define WS_IDX       147456     // int[32768]
#define WS_Z2        278528     // float[32768]
#define WS_E2        409600     // float[4096]
#define WS_RMAX      425984     // uint[32768]
#define WS_CNT       557056     // int[32768]
#define WS_DW        688128     // float[1048576] -> ends 4882432

// ---- d_out scratch (d_out = 42.09 MB total; all regions rewritten later) ----
#define DO_ZB        0          // ushort[32768*256] = 16 MB
#define DO_WB        16777216   // ushort[4096*256]  =  2 MB
#define DO_CAND      18874368   // int[32768*128]    = 16 MB -> ends 35651584

typedef __attribute__((ext_vector_type(8)))  short bf16x8;
typedef __attribute__((ext_vector_type(16))) float f32x16;
typedef __attribute__((ext_vector_type(8)))  unsigned short us8;

// ---------------------------------------------------------------------------
// K1: z2/e2 with numpy's exact pairwise structure (proven in R1)
// ---------------------------------------------------------------------------
__global__ void k1_norms(const float* __restrict__ z, const float* __restrict__ w,
                         float* __restrict__ z2, float* __restrict__ e2)
{
#pragma clang fp contract(off)
    int gid = blockIdx.x * blockDim.x + threadIdx.x;
    const float* row;
    float* outp;
    if (gid < N_ROWS) { row = z + (size_t)gid * D_DIM; outp = z2 + gid; }
    else if (gid < N_ROWS + K_CODES) { row = w + (size_t)(gid - N_ROWS) * D_DIM; outp = e2 + (gid - N_ROWS); }
    else return;

    float total = 0.0f;
    for (int half = 0; half < 2; half++) {
        const float* x = row + half * 128;
        float r[8];
#pragma unroll
        for (int j = 0; j < 8; j++) { float v = x[j]; r[j] = v * v; }
        for (int i = 8; i < 128; i += 8) {
#pragma unroll
            for (int j = 0; j < 8; j++) { float v = x[i + j]; r[j] += v * v; }
        }
        float s = ((r[0] + r[1]) + (r[2] + r[3])) + ((r[4] + r[5]) + (r[6] + r[7]));
        if (half == 0) total = s; else total = total + s;
    }
    *outp = total;
}

// ---------------------------------------------------------------------------
// KCONV: fp32 -> bf16 (RNE), 8 elems/thread. z then w.
// ---------------------------------------------------------------------------
__device__ inline unsigned short f2b(float f) {
    __hip_bfloat16 h = __float2bfloat16(f);
    return *(unsigned short*)&h;
}

__global__ void kconv(const float* __restrict__ z, const float* __restrict__ w,
                      unsigned short* __restrict__ zb, unsigned short* __restrict__ wb)
{
    size_t i = (size_t)(blockIdx.x * 256 + threadIdx.x) * 8;
    const float* src; unsigned short* dst;
    const size_t NZ = (size_t)N_ROWS * D_DIM;
    if (i < NZ) { src = z + i; dst = zb + i; }
    else        { size_t j = i - NZ; src = w + j; dst = wb + j; }
    float4 a = *(const float4*)src;
    float4 b = *(const float4*)(src + 4);
    us8 o;
    o[0] = f2b(a.x); o[1] = f2b(a.y); o[2] = f2b(a.z); o[3] = f2b(a.w);
    o[4] = f2b(b.x); o[5] = f2b(b.y); o[6] = f2b(b.z); o[7] = f2b(b.w);
    *(us8*)dst = o;
}

// ---------------------------------------------------------------------------
// K2 (two phases): bf16 MFMA GEMM t = W @ Z^T, 128-code x 128-row tiles.
// 256 thr = 4 waves (2x2), wave tile 64x64, 32x32x16 MFMA.
// Staging: us8 global loads -> registers -> LDS stores, double-buffered.
// PHASE 0: per-row max t~ -> atomicMax (ordered-uint key).
// PHASE 1: bit-identical recompute; append codes with t~ >= rowmax - margin.
// ---------------------------------------------------------------------------
template<int PHASE>
__global__ __launch_bounds__(256, 2) void k2_pass(
    const unsigned short* __restrict__ zb, const unsigned short* __restrict__ wb,
    unsigned int* __restrict__ rowmaxkey, int* __restrict__ cnt,
    int* __restrict__ cand)
{
    __shared__ char smem[65536];
    const int tid  = threadIdx.x;
    const int lane = tid & 63;
    const int wid  = tid >> 6;
    const int wr   = wid >> 1;
    const int wc   = wid & 1;
    const int rowBase  = blockIdx.x * 128;
    const int codeBase = blockIdx.y * 2048;
    const int m = lane & 31;

    int rown[2];
#pragma unroll
    for (int ns = 0; ns < 2; ns++) rown[ns] = rowBase + wc * 64 + ns * 32 + m;

    float thr[2];
    if (PHASE == 1) {
#pragma unroll
        for (int ns = 0; ns < 2; ns++) {
            unsigned u = rowmaxkey[rown[ns]];
            int b = (u & 0x80000000u) ? (int)(u ^ 0x80000000u) : (int)~u;
            thr[ns] = __int_as_float(b) - MARGIN_T;
        }
    }

    us8 va[4], vb[4];
    auto load_regs = [&](int c) {
        int ct = c >> 2, ch = c & 3;
        int col8 = ch * 64 + wid * 16 + (lane >> 5) * 8;
#pragma unroll
        for (int g = 0; g < 4; g++) {
            int arow = codeBase + ct * 128 + g * 32 + m;
            int brow = rowBase + g * 32 + m;
            va[g] = *(const us8*)(wb + (size_t)arow * D_DIM + col8);
            vb[g] = *(const us8*)(zb + (size_t)brow * D_DIM + col8);
        }
    };
    auto write_lds = [&](int buf) {
        char* Ab = smem + buf * 32768;
        char* Bb = Ab + 16384;
#pragma unroll
        for (int g = 0; g < 4; g++) {
            *(us8*)(Ab + (size_t)((wid * 4 + g) * 64 + lane) * 16) = va[g];
            *(us8*)(Bb + (size_t)((wid * 4 + g) * 64 + lane) * 16) = vb[g];
        }
    };

    f32x16 acc[2][2];
    float tmax[2] = {-1e30f, -1e30f};

    load_regs(0);
    write_lds(0);

    const int NCH = 64;                  // 16 code-tiles * 4 d-chunks
    for (int c = 0; c < NCH; c++) {
        const int buf = c & 1;
        __syncthreads();
        if (c + 1 < NCH) {
            load_regs(c + 1);
            write_lds(buf ^ 1);
        }
        const char* Ab = smem + buf * 32768;
        const char* Bb = Ab + 16384;
        if ((c & 3) == 0) {
            f32x16 zz = {};
#pragma unroll
            for (int ms = 0; ms < 2; ms++)
#pragma unroll
                for (int ns = 0; ns < 2; ns++) acc[ms][ns] = zz;
        }
#pragma unroll
        for (int s = 0; s < 4; s++) {
            bf16x8 af[2], bfr[2];
#pragma unroll
            for (int ms = 0; ms < 2; ms++)
                af[ms] = *(const bf16x8*)(Ab + (size_t)(s * 256 + (wr * 2 + ms) * 64 + lane) * 16);
#pragma unroll
            for (int ns = 0; ns < 2; ns++)
                bfr[ns] = *(const bf16x8*)(Bb + (size_t)(s * 256 + (wc * 2 + ns) * 64 + lane) * 16);
#pragma unroll
            for (int ms = 0; ms < 2; ms++)
#pragma unroll
                for (int ns = 0; ns < 2; ns++)
                    acc[ms][ns] = __builtin_amdgcn_mfma_f32_32x32x16_bf16(
                        af[ms], bfr[ns], acc[ms][ns], 0, 0, 0);
        }
        if ((c & 3) == 3) {
            const int ct = c >> 2;
            if (PHASE == 0) {
#pragma unroll
                for (int ms = 0; ms < 2; ms++)
#pragma unroll
                    for (int ns = 0; ns < 2; ns++)
#pragma unroll
                        for (int r = 0; r < 16; r++)
                            tmax[ns] = fmaxf(tmax[ns], acc[ms][ns][r]);
            } else {
#pragma unroll
                for (int ms = 0; ms < 2; ms++)
#pragma unroll
                    for (int ns = 0; ns < 2; ns++)
#pragma unroll
                        for (int r = 0; r < 16; r++) {
                            float v = acc[ms][ns][r];
                            if (v >= thr[ns]) {
                                int code = codeBase + ct * 128 + wr * 64 + ms * 32
                                         + ((r & 3) + 8 * (r >> 2) + 4 * (lane >> 5));
                                int n = rown[ns];
                                int slot = atomicAdd(&cnt[n], 1);
                                if (slot < CAP) cand[(size_t)n * CAP + slot] = code;
                            }
                        }
            }
        }
    }

    if (PHASE == 0) {
#pragma unroll
        for (int ns = 0; ns < 2; ns++) {
            float o = __shfl_xor(tmax[ns], 32);
            float mx = fmaxf(tmax[ns], o);
            if (lane < 32) {
                int b = __float_as_int(mx);
                unsigned key = (unsigned)b ^ ((unsigned)(b >> 31) | 0x80000000u);
                atomicMax(&rowmaxkey[rown[ns]], key);
            }
        }
    }
}

// ---------------------------------------------------------------------------
// K_RESCORE v4: one WAVE (64 thr) per row; batches of RB=8 candidates.
// Staging uses k2's proven split pattern: 8 independent coalesced float4
// loads issued into registers (prefetched during the previous batch's
// chain), then 8 LDS writes. LDS 9.3 KB -> 16 blocks/CU (50% occupancy).
// Chain: lane i runs candidate i's 256-FMA serial chain from LDS
// (ascending d, single accumulator = bit-identical to BLAS sgemm).
// Wave-wide lexicographic (d,k) butterfly -> first-index tie-break.
// Fallback full 4096 scan if cnt==0 or cnt>CAP.
// ---------------------------------------------------------------------------
__global__ __launch_bounds__(64) void k_rescore(
    const float* __restrict__ z, const float* __restrict__ w,
    const float* __restrict__ z2, const float* __restrict__ e2,
    const int* __restrict__ cnt, const int* __restrict__ cand,
    int* __restrict__ idx_out)
{
#pragma clang fp contract(off)
    const int lane = threadIdx.x;
    const int n    = blockIdx.x;

    __shared__ float4 wst[RB * 65];   // 8320 B, slot j at wst[j*65 + d4]
    __shared__ float4 zst[64];        // z row, 1 KB

    zst[lane] = ((const float4*)(z + (size_t)n * D_DIM))[lane];

    int c = cnt[n];
    const bool fallback = (c <= 0) || (c > CAP);
    const int total = fallback ? K_CODES : c;

    float bd = __builtin_inff(); int bk = K_CODES;
    const float z2v = z2[n];

    float4 regs[RB];
    auto load_regs = [&](int base) {
#pragma unroll
        for (int j = 0; j < RB; j++) {
            int s = base + j;
            int k = 0;
            if (s < total) {
                k = fallback ? s : cand[(size_t)n * CAP + s];
                if ((unsigned)k >= (unsigned)K_CODES) k = 0;   // defensive
            }
            regs[j] = ((const float4*)(w + (size_t)k * D_DIM))[lane];
        }
    };

    load_regs(0);
    for (int base = 0; base < total; base += RB) {
        int nb = total - base; if (nb > RB) nb = RB;
#pragma unroll
        for (int j = 0; j < RB; j++) wst[j * 65 + lane] = regs[j];
        if (base + RB < total) load_regs(base + RB);   // prefetch during chain
        __syncthreads();
        if (lane < nb) {
            int k = fallback ? (base + lane) : cand[(size_t)n * CAP + base + lane];
            if ((unsigned)k >= (unsigned)K_CODES) k = 0;   // defensive
            const float4* wp = &wst[lane * 65];
            float tacc = 0.0f;
#pragma unroll
            for (int d4 = 0; d4 < 64; d4++) {
                float4 wv = wp[d4];
                float4 zv = zst[d4];
                tacc = __builtin_fmaf(zv.x, wv.x, tacc);
                tacc = __builtin_fmaf(zv.y, wv.y, tacc);
                tacc = __builtin_fmaf(zv.z, wv.z, tacc);
                tacc = __builtin_fmaf(zv.w, wv.w, tacc);
            }
            float u  = z2v - 2.0f * tacc;   // 2*tacc exact -> single rounding
            float dv = u + e2[k];
            if (dv < bd || (dv == bd && k < bk)) { bd = dv; bk = k; }
        }
        __syncthreads();
    }

#pragma unroll
    for (int off = 1; off < 64; off <<= 1) {
        float od = __shfl_xor(bd, off);
        int   ok = __shfl_xor(bk, off);
        if (od < bd || (od == bd && ok < bk)) { bd = od; bk = ok; }
    }
    if (lane == 0) idx_out[n] = bk;
}

// ---------------------------------------------------------------------------
// K3: gather z_q, STE output, loss partials, counts + dw atomics.
// ---------------------------------------------------------------------------
__global__ void k3_scatter(const float* __restrict__ z, const float* __restrict__ w,
                           const int* __restrict__ idx_in,
                           float* __restrict__ counts, float* __restrict__ lossp,
                           float* __restrict__ dw, float* __restrict__ out_zq,
                           float* __restrict__ out_idx)
{
#pragma clang fp contract(off)
    const int n = blockIdx.x;
    const int t = threadIdx.x;
    int idx = idx_in[n];
    if (idx < 0) idx = 0;
    if (idx >= K_CODES) idx = K_CODES - 1;     // defensive clamp (no fault)
    if (t == 0) {
        out_idx[n] = (float)idx;
        atomicAdd(&counts[idx], 1.0f);
    }
    float zv = z[(size_t)n * D_DIM + t];
    float wq = w[(size_t)idx * D_DIM + t];
    out_zq[(size_t)n * D_DIM + t] = zv + (wq - zv);
    float df = zv - wq;
    float sq = df * df;
    atomicAdd(&dw[(size_t)idx * D_DIM + t], zv);

    __shared__ float red[256];
    red[t] = sq; __syncthreads();
    for (int s = 128; s > 0; s >>= 1) {
        if (t < s) red[t] += red[t + s];
        __syncthreads();
    }
    if (t == 0) lossp[n] = red[0];
}

// ---------------------------------------------------------------------------
// K4: vq_loss finalize + new_cs (Laplace smoothing). Single block, 1024 thr.
// ---------------------------------------------------------------------------
__global__ void k4_cs(const float* __restrict__ lossp, const float* __restrict__ counts,
                      const float* __restrict__ cs_in, float* __restrict__ out_loss,
                      float* __restrict__ out_cs)
{
#pragma clang fp contract(off)
    const int t = threadIdx.x;
    __shared__ float red[1024];
    __shared__ float pre[K_CODES];

    float s = 0.0f;
    for (int i = t; i < N_ROWS; i += 1024) s += lossp[i];
    red[t] = s; __syncthreads();
    for (int st = 512; st > 0; st >>= 1) {
        if (t < st) red[t] += red[t + st];
        __syncthreads();
    }
    if (t == 0) out_loss[0] = 0.25f * (red[0] / 8388608.0f);
    __syncthreads();

    const float DEC = 0.99f;
    const float OMD = (float)(1.0 - 0.99);
    float mine[4];
#pragma unroll
    for (int q = 0; q < 4; q++) {
        int k = t + q * 1024;
        float t1 = DEC * cs_in[k];
        float t2 = OMD * counts[k];
        float p = t1 + t2;
        pre[k] = p; mine[q] = p;
    }
    float psum = (mine[0] + mine[1]) + (mine[2] + mine[3]);
    red[t] = psum; __syncthreads();
    for (int st = 512; st > 0; st >>= 1) {
        if (t < st) red[t] += red[t + st];
        __syncthreads();
    }
    float nsum = red[0];
    const float KEPS = (float)(4096.0 * 1e-5);
    float denom = nsum + KEPS;
#pragma unroll
    for (int q = 0; q < 4; q++) {
        int k = t + q * 1024;
        float v = ((pre[k] + 1e-5f) / denom) * nsum;
        out_cs[k] = v;
    }
}

// ---------------------------------------------------------------------------
// K5: new_ema_w = 0.99*ema_w + 0.01*dw ; new_weight = new_ema_w / new_cs[k]
// ---------------------------------------------------------------------------
__global__ void k5_emaw(const float* __restrict__ ema_w, const float* __restrict__ dw,
                        const float* __restrict__ newcs, float* __restrict__ out_w,
                        float* __restrict__ out_emaw)
{
#pragma clang fp contract(off)
    const int i = blockIdx.x * 256 + threadIdx.x;
    const int k = i >> 8;
    const float OMD = (float)(1.0 - 0.99);
    float t1 = 0.99f * ema_w[i];
    float t2 = OMD * dw[i];
    float ne = t1 + t2;
    out_emaw[i] = ne;
    out_w[i] = ne / newcs[k];
}

extern "C" void kernel_launch(void* const* d_in, const int* in_sizes, int n_in,
                              void* d_out, int out_size, void* d_ws, size_t ws_size,
                              hipStream_t stream)
{
    const float* z    = (const float*)d_in[0];
    const float* w    = (const float*)d_in[1];
    const float* cs   = (const float*)d_in[2];
    const float* emaw = (const float*)d_in[3];

    float* out      = (float*)d_out;
    float* out_zq   = out;                    // 8388608
    float* out_idx  = out + 8388608;          // 32768
    float* out_loss = out + 8421376;          // 1
    float* out_w    = out + 8421377;          // 1048576
    float* out_cs   = out + 9469953;          // 4096
    float* out_emaw = out + 9474049;          // 1048576

    char* ws = (char*)d_ws;
    float*          counts  = (float*)(ws + WS_COUNTS);
    float*          lossp   = (float*)(ws + WS_LOSSP);
    int*            idx_int = (int*)  (ws + WS_IDX);
    float*          z2      = (float*)(ws + WS_Z2);
    float*          e2      = (float*)(ws + WS_E2);
    unsigned int*   rmax    = (unsigned int*)(ws + WS_RMAX);
    int*            cnt     = (int*)  (ws + WS_CNT);
    float*          dw      = (float*)(ws + WS_DW);

    // big scratch lives in d_out (fully rewritten by k3/k4/k5 afterwards)
    char* ob = (char*)d_out;
    unsigned short* zb   = (unsigned short*)(ob + DO_ZB);
    unsigned short* wb   = (unsigned short*)(ob + DO_WB);
    int*            cand = (int*)           (ob + DO_CAND);

    hipMemsetAsync(counts, 0, K_CODES * sizeof(float), stream);
    hipMemsetAsync(dw, 0, (size_t)K_CODES * D_DIM * sizeof(float), stream);
    hipMemsetAsync(rmax, 0, N_ROWS * sizeof(unsigned int), stream);
    hipMemsetAsync(cnt, 0, N_ROWS * sizeof(int), stream);

    k1_norms<<<(N_ROWS + K_CODES) / 256, 256, 0, stream>>>(z, w, z2, e2);
    kconv<<<(N_ROWS + K_CODES) * D_DIM / (256 * 8), 256, 0, stream>>>(z, w, zb, wb);

    dim3 g2(N_ROWS / 128, 2);
    k2_pass<0><<<g2, 256, 0, stream>>>(zb, wb, rmax, cnt, cand);
    k2_pass<1><<<g2, 256, 0, stream>>>(zb, wb, rmax, cnt, cand);

    k_rescore<<<N_ROWS, 64, 0, stream>>>(z, w, z2, e2, cnt, cand, idx_int);

    k3_scatter<<<N_ROWS, 256, 0, stream>>>(z, w, idx_int, counts, lossp,
                                           dw, out_zq, out_idx);

    k4_cs<<<1, 1024, 0, stream>>>(lossp, counts, cs, out_loss, out_cs);

    k5_emaw<<<K_CODES, 256, 0, stream>>>(emaw, dw, out_cs, out_w, out_emaw);
}